// Round 1
// baseline (412.606 us; speedup 1.0000x reference)
//
#include <hip/hip_runtime.h>

// EncConvNet fused v3: conv7x7s3+sq -> fc1+sq -> fc2, one kernel.
// v2 -> v3: occupancy attack. 1024 threads/block (16 waves/CU = 4/SIMD,
// was 2/SIMD), same 64 images/block, LDS ~139.8 KB (1 block/CU).
//  - conv chunk 8 -> 16 images, xbuf SINGLE-buffered (same 12544-float
//    footprint as v2's double buffer); register prefetch still hides HBM
//    latency under conv compute. Per-wave LDS instr count unchanged.
//  - hb pitch 64 -> 65 float4: v2's conv->h write had all 64 lanes in one
//    4-bank group (img uniform, k4 varies; first-bank=(4*img)%32). Pitch 65
//    gives first-bank=(4*k4+4*img)%32 -> ideal 8 words/bank. fc1 read side
//    (lanes vary img) stays contiguous/conflict-free.
//  - fc1: 16 waves x 4 outputs (was 8x8), weights still wave-uniform s_load,
//    unroll 4 to keep more SMEM loads in flight; lighter VGPR/SGPR pressure.

#define BLK_IMGS    64
#define CHUNK_IMGS  16
#define NCHUNK      4
#define XCH_FLOATS  (CHUNK_IMGS * 784)   // 12544 floats per chunk
#define HB_PITCH    65                   // float4 pitch (bank-conflict pad)

// LDS float offsets
#define LDS_XBUF    0                    // 12544 (single buffer)
#define LDS_H       12544                // 64*65 float4 = 16640 floats
#define LDS_H2      29184                // 16*64 float4 = 4096 floats
#define LDS_W2      33280                // 256 float4 = 1024 floats
#define LDS_OUT     34304                // 640 floats
#define LDS_TOTAL_F 34944                // -> 139776 bytes

__global__ __launch_bounds__(1024, 4)
void encconv_fused3(const float* __restrict__ x,
                    const float* __restrict__ conv_w,
                    const float* __restrict__ conv_b,
                    const float* __restrict__ fc1_w,
                    const float* __restrict__ fc1_b,
                    const float* __restrict__ fc2_w,
                    const float* __restrict__ fc2_b,
                    float* __restrict__ out)
{
    extern __shared__ float lds[];
    float*  xbuf = lds + LDS_XBUF;
    float4* hb   = (float4*)(lds + LDS_H);
    float4* h2b  = (float4*)(lds + LDS_H2);
    float4* w2b  = (float4*)(lds + LDS_W2);
    float*  ob   = lds + LDS_OUT;

    const int tid = threadIdx.x;
    const int blk = blockIdx.x;
    const long base_img = (long)blk * BLK_IMGS;

    // ---- conv-phase thread roles: tid = g*64 + y*8 + c*2 + xh ----
    const int g  = tid >> 6;         // wave id == image-in-chunk, 0..15
    const int y  = (tid >> 3) & 7;   // conv output row
    const int c  = (tid >> 1) & 3;   // channel
    const int xh = tid & 1;          // x-half (outputs 4*xh .. 4*xh+3)

    // per-lane conv taps for channel c (one-time, L1-broadcast across lanes)
    float wv[49];
    #pragma unroll
    for (int i = 0; i < 49; ++i) wv[i] = conv_w[c * 49 + i];
    const float cb = conv_b[c];

    // stage fc2_w into LDS, k-major: slot = kk*16 + j
    if (tid < 160) {
        float4 v = *(const float4*)(fc2_w + tid * 4);
        int e  = tid * 4;
        int j  = e >> 6;          // 0..9
        int kk = (e & 63) >> 2;   // 0..15
        w2b[kk * 16 + j] = v;
    }

    const float* xblk = x + base_img * 784;

    // ---- prefetch chunk 0 into registers (coalesced: 3136 float4) ----
    float4 pf0, pf1, pf2, pf3;
    {
        const float* src = xblk;
        pf0 = *(const float4*)(src + 4 * tid);
        pf1 = *(const float4*)(src + 4 * (tid + 1024));
        pf2 = *(const float4*)(src + 4 * (tid + 2048));
        if (tid < 64) pf3 = *(const float4*)(src + 4 * (tid + 3072));
    }

    // ---- conv over 4 chunks of 16 images, single-buffered LDS ----
    for (int ch = 0; ch < NCHUNK; ++ch) {
        // commit prefetched regs to LDS (lane-contiguous ds_write_b128)
        *(float4*)(xbuf + 4 * tid)          = pf0;
        *(float4*)(xbuf + 4 * (tid + 1024)) = pf1;
        *(float4*)(xbuf + 4 * (tid + 2048)) = pf2;
        if (tid < 64) *(float4*)(xbuf + 4 * (tid + 3072)) = pf3;
        __syncthreads();

        // issue next chunk's prefetch; conv compute below hides its latency
        if (ch + 1 < NCHUNK) {
            const float* src = xblk + (ch + 1) * XCH_FLOATS;
            pf0 = *(const float4*)(src + 4 * tid);
            pf1 = *(const float4*)(src + 4 * (tid + 1024));
            pf2 = *(const float4*)(src + 4 * (tid + 2048));
            if (tid < 64) pf3 = *(const float4*)(src + 4 * (tid + 3072));
        }

        // conv: image g of this chunk, row y, channel c, outputs 4xh..4xh+3
        float acc0 = 0.f, acc1 = 0.f, acc2 = 0.f, acc3 = 0.f;
        const float* xi = xbuf + g * 784;
        #pragma unroll
        for (int rr = 0; rr < 7; ++rr) {
            const float* rp = xi + (3 * y + rr) * 28 + 12 * xh;  // 16B aligned
            float4 r0 = *(const float4*)(rp + 0);
            float4 r1 = *(const float4*)(rp + 4);
            float4 r2 = *(const float4*)(rp + 8);
            float4 r3 = *(const float4*)(rp + 12);
            float r[16] = { r0.x, r0.y, r0.z, r0.w,
                            r1.x, r1.y, r1.z, r1.w,
                            r2.x, r2.y, r2.z, r2.w,
                            r3.x, r3.y, r3.z, r3.w };
            #pragma unroll
            for (int kx = 0; kx < 7; ++kx) {
                const float w = wv[rr * 7 + kx];
                acc0 = fmaf(r[0 + kx], w, acc0);
                acc1 = fmaf(r[3 + kx], w, acc1);
                acc2 = fmaf(r[6 + kx], w, acc2);
                acc3 = fmaf(r[9 + kx], w, acc3);
            }
        }

        // bias + square -> h (k-major, padded pitch: slot = k4*65 + img)
        float4 hv;
        hv.x = acc0 + cb; hv.x *= hv.x;
        hv.y = acc1 + cb; hv.y *= hv.y;
        hv.z = acc2 + cb; hv.z *= hv.z;
        hv.w = acc3 + cb; hv.w *= hv.w;
        hb[(c * 16 + y * 2 + xh) * HB_PITCH + (ch * CHUNK_IMGS + g)] = hv;

        // conv reads of xbuf must finish before next chunk's commit;
        // this barrier also publishes hb for fc1 after the last chunk.
        __syncthreads();
    }

    // ---- fc1: wave w4 (0..15) -> outputs 4*w4..4*w4+3, lanes = 64 images ----
    {
        const int img = tid & 63;
        const int w4  = __builtin_amdgcn_readfirstlane(tid >> 6);  // uniform
        const float* wbase = fc1_w + (w4 * 4) * 256;

        float a0 = 0.f, a1 = 0.f, a2 = 0.f, a3 = 0.f;

        #pragma unroll 4
        for (int k4 = 0; k4 < 64; ++k4) {
            float4 h4 = hb[k4 * HB_PITCH + img];          // lane-contiguous b128
            const float* wp = wbase + k4 * 4;
            float4 w0 = *(const float4*)(wp + 0 * 256);   // uniform -> s_load
            float4 w1 = *(const float4*)(wp + 1 * 256);
            float4 w2 = *(const float4*)(wp + 2 * 256);
            float4 w3 = *(const float4*)(wp + 3 * 256);
            a0 = fmaf(h4.x,w0.x,a0); a0 = fmaf(h4.y,w0.y,a0); a0 = fmaf(h4.z,w0.z,a0); a0 = fmaf(h4.w,w0.w,a0);
            a1 = fmaf(h4.x,w1.x,a1); a1 = fmaf(h4.y,w1.y,a1); a1 = fmaf(h4.z,w1.z,a1); a1 = fmaf(h4.w,w1.w,a1);
            a2 = fmaf(h4.x,w2.x,a2); a2 = fmaf(h4.y,w2.y,a2); a2 = fmaf(h4.z,w2.z,a2); a2 = fmaf(h4.w,w2.w,a2);
            a3 = fmaf(h4.x,w3.x,a3); a3 = fmaf(h4.y,w3.y,a3); a3 = fmaf(h4.z,w3.z,a3); a3 = fmaf(h4.w,w3.w,a3);
        }

        // bias + square -> h2 (k-major: k4 == w4), lane-contiguous b128 write
        const float* bp = fc1_b + w4 * 4;   // uniform -> s_load
        float4 p0;
        p0.x = a0 + bp[0]; p0.x *= p0.x;
        p0.y = a1 + bp[1]; p0.y *= p0.y;
        p0.z = a2 + bp[2]; p0.z *= p0.z;
        p0.w = a3 + bp[3]; p0.w *= p0.w;
        h2b[w4 * 64 + img] = p0;
    }
    __syncthreads();

    // ---- fc2: first 512 threads; (im3 = t>>3, q = t&7); j = q, and 8+q for q<2 ----
    if (tid < 512) {
        const int im3 = tid >> 3;
        const int q   = tid & 7;

        float s1 = 0.f;
        #pragma unroll
        for (int k4 = 0; k4 < 16; ++k4) {
            float4 hh = h2b[k4 * 64 + im3];
            float4 wA = w2b[k4 * 16 + q];
            s1 = fmaf(hh.x, wA.x, s1); s1 = fmaf(hh.y, wA.y, s1);
            s1 = fmaf(hh.z, wA.z, s1); s1 = fmaf(hh.w, wA.w, s1);
        }
        ob[im3 * 10 + q] = s1 + fc2_b[q];

        if (q < 2) {
            float s2 = 0.f;
            #pragma unroll
            for (int k4 = 0; k4 < 16; ++k4) {
                float4 hh = h2b[k4 * 64 + im3];
                float4 wB = w2b[k4 * 16 + 8 + q];
                s2 = fmaf(hh.x, wB.x, s2); s2 = fmaf(hh.y, wB.y, s2);
                s2 = fmaf(hh.z, wB.z, s2); s2 = fmaf(hh.w, wB.w, s2);
            }
            ob[im3 * 10 + 8 + q] = s2 + fc2_b[8 + q];
        }
    }
    __syncthreads();

    // ---- coalesced output store: 640 floats per block ----
    if (tid < 160) {
        float4 v = *(const float4*)(ob + tid * 4);
        *(float4*)(out + (long)blk * 640 + tid * 4) = v;
    }
}

extern "C" void kernel_launch(void* const* d_in, const int* in_sizes, int n_in,
                              void* d_out, int out_size, void* d_ws, size_t ws_size,
                              hipStream_t stream) {
    const float* x      = (const float*)d_in[0];
    const float* conv_w = (const float*)d_in[1];
    const float* conv_b = (const float*)d_in[2];
    const float* fc1_w  = (const float*)d_in[3];
    const float* fc1_b  = (const float*)d_in[4];
    const float* fc2_w  = (const float*)d_in[5];
    const float* fc2_b  = (const float*)d_in[6];
    float* out = (float*)d_out;

    const int B = in_sizes[0] / 784;
    const int blocks = (B + BLK_IMGS - 1) / BLK_IMGS;   // 1024 for B=65536
    const size_t lds_bytes = LDS_TOTAL_F * sizeof(float);  // 139776

    // gfx950 allows 160 KiB LDS/workgroup; raise the dynamic-LDS cap (idempotent).
    static bool attr_set = false;
    if (!attr_set) {
        (void)hipFuncSetAttribute((const void*)encconv_fused3,
                                  hipFuncAttributeMaxDynamicSharedMemorySize,
                                  (int)lds_bytes);
        attr_set = true;
    }

    encconv_fused3<<<blocks, 1024, lds_bytes, stream>>>(
        x, conv_w, conv_b, fc1_w, fc1_b, fc2_w, fc2_b, out);
}

// Round 2
// 409.004 us; speedup vs baseline: 1.0088x; 1.0088x over previous
//
#include <hip/hip_runtime.h>

// EncConvNet fused v4: conv7x7s3+sq -> fc1+sq -> fc2, one kernel.
// v3 -> v4: SPILL FIX. v3's __launch_bounds__(1024,4) only sets a MIN
// waves/EU; the allocator squeezed to 64 VGPR (chasing occupancy that LDS
// already caps at 1 block/CU) and spilled the 49-element conv-tap array:
// WRITE_SIZE 2.9 MB -> 194 MB of scratch. amdgpu_waves_per_eu(4,4) pins
// min=max=4 -> VGPR budget 128, no spills (v2 ran this conv at 128 VGPR
// spill-free).
//  - 1024 threads/block, 64 images/block, LDS 139.8 KB -> 1 block/CU,
//    16 waves/CU = 4/SIMD (OccupancyPercent ~45, was 22 in v2).
//  - hb pitch 65 float4: conv->h write spreads 64 lanes over all banks
//    (8 words/bank, optimal); fc1 read side contiguous/conflict-free.
//  - fc1: 16 waves x 4 outputs, weights wave-uniform -> s_load_dwordx4.

#define BLK_IMGS    64
#define CHUNK_IMGS  16
#define NCHUNK      4
#define XCH_FLOATS  (CHUNK_IMGS * 784)   // 12544 floats per chunk
#define HB_PITCH    65                   // float4 pitch (bank-conflict pad)

// LDS float offsets
#define LDS_XBUF    0                    // 12544 (single buffer)
#define LDS_H       12544                // 64*65 float4 = 16640 floats
#define LDS_H2      29184                // 16*64 float4 = 4096 floats
#define LDS_W2      33280                // 256 float4 = 1024 floats
#define LDS_OUT     34304                // 640 floats
#define LDS_TOTAL_F 34944                // -> 139776 bytes

__global__ __launch_bounds__(1024)
__attribute__((amdgpu_waves_per_eu(4, 4)))
void encconv_fused4(const float* __restrict__ x,
                    const float* __restrict__ conv_w,
                    const float* __restrict__ conv_b,
                    const float* __restrict__ fc1_w,
                    const float* __restrict__ fc1_b,
                    const float* __restrict__ fc2_w,
                    const float* __restrict__ fc2_b,
                    float* __restrict__ out)
{
    extern __shared__ float lds[];
    float*  xbuf = lds + LDS_XBUF;
    float4* hb   = (float4*)(lds + LDS_H);
    float4* h2b  = (float4*)(lds + LDS_H2);
    float4* w2b  = (float4*)(lds + LDS_W2);
    float*  ob   = lds + LDS_OUT;

    const int tid = threadIdx.x;
    const int blk = blockIdx.x;
    const long base_img = (long)blk * BLK_IMGS;

    // ---- conv-phase thread roles: tid = g*64 + y*8 + c*2 + xh ----
    const int g  = tid >> 6;         // wave id == image-in-chunk, 0..15
    const int y  = (tid >> 3) & 7;   // conv output row
    const int c  = (tid >> 1) & 3;   // channel
    const int xh = tid & 1;          // x-half (outputs 4*xh .. 4*xh+3)

    // per-lane conv taps for channel c (one-time, L1-broadcast across lanes)
    float wv[49];
    #pragma unroll
    for (int i = 0; i < 49; ++i) wv[i] = conv_w[c * 49 + i];
    const float cb = conv_b[c];

    // stage fc2_w into LDS, k-major: slot = kk*16 + j
    if (tid < 160) {
        float4 v = *(const float4*)(fc2_w + tid * 4);
        int e  = tid * 4;
        int j  = e >> 6;          // 0..9
        int kk = (e & 63) >> 2;   // 0..15
        w2b[kk * 16 + j] = v;
    }

    const float* xblk = x + base_img * 784;

    // ---- prefetch chunk 0 into registers (coalesced: 3136 float4) ----
    float4 pf0, pf1, pf2, pf3;
    {
        const float* src = xblk;
        pf0 = *(const float4*)(src + 4 * tid);
        pf1 = *(const float4*)(src + 4 * (tid + 1024));
        pf2 = *(const float4*)(src + 4 * (tid + 2048));
        if (tid < 64) pf3 = *(const float4*)(src + 4 * (tid + 3072));
    }

    // ---- conv over 4 chunks of 16 images, single-buffered LDS ----
    for (int ch = 0; ch < NCHUNK; ++ch) {
        // commit prefetched regs to LDS (lane-contiguous ds_write_b128)
        *(float4*)(xbuf + 4 * tid)          = pf0;
        *(float4*)(xbuf + 4 * (tid + 1024)) = pf1;
        *(float4*)(xbuf + 4 * (tid + 2048)) = pf2;
        if (tid < 64) *(float4*)(xbuf + 4 * (tid + 3072)) = pf3;
        __syncthreads();

        // issue next chunk's prefetch; conv compute below hides its latency
        if (ch + 1 < NCHUNK) {
            const float* src = xblk + (ch + 1) * XCH_FLOATS;
            pf0 = *(const float4*)(src + 4 * tid);
            pf1 = *(const float4*)(src + 4 * (tid + 1024));
            pf2 = *(const float4*)(src + 4 * (tid + 2048));
            if (tid < 64) pf3 = *(const float4*)(src + 4 * (tid + 3072));
        }

        // conv: image g of this chunk, row y, channel c, outputs 4xh..4xh+3
        float acc0 = 0.f, acc1 = 0.f, acc2 = 0.f, acc3 = 0.f;
        const float* xi = xbuf + g * 784;
        #pragma unroll
        for (int rr = 0; rr < 7; ++rr) {
            const float* rp = xi + (3 * y + rr) * 28 + 12 * xh;  // 16B aligned
            float4 r0 = *(const float4*)(rp + 0);
            float4 r1 = *(const float4*)(rp + 4);
            float4 r2 = *(const float4*)(rp + 8);
            float4 r3 = *(const float4*)(rp + 12);
            float r[16] = { r0.x, r0.y, r0.z, r0.w,
                            r1.x, r1.y, r1.z, r1.w,
                            r2.x, r2.y, r2.z, r2.w,
                            r3.x, r3.y, r3.z, r3.w };
            #pragma unroll
            for (int kx = 0; kx < 7; ++kx) {
                const float w = wv[rr * 7 + kx];
                acc0 = fmaf(r[0 + kx], w, acc0);
                acc1 = fmaf(r[3 + kx], w, acc1);
                acc2 = fmaf(r[6 + kx], w, acc2);
                acc3 = fmaf(r[9 + kx], w, acc3);
            }
        }

        // bias + square -> h (k-major, padded pitch: slot = k4*65 + img)
        float4 hv;
        hv.x = acc0 + cb; hv.x *= hv.x;
        hv.y = acc1 + cb; hv.y *= hv.y;
        hv.z = acc2 + cb; hv.z *= hv.z;
        hv.w = acc3 + cb; hv.w *= hv.w;
        hb[(c * 16 + y * 2 + xh) * HB_PITCH + (ch * CHUNK_IMGS + g)] = hv;

        // conv reads of xbuf must finish before next chunk's commit;
        // this barrier also publishes hb for fc1 after the last chunk.
        __syncthreads();
    }

    // ---- fc1: wave w4 (0..15) -> outputs 4*w4..4*w4+3, lanes = 64 images ----
    {
        const int img = tid & 63;
        const int w4  = __builtin_amdgcn_readfirstlane(tid >> 6);  // uniform
        const float* wbase = fc1_w + (w4 * 4) * 256;

        float a0 = 0.f, a1 = 0.f, a2 = 0.f, a3 = 0.f;

        #pragma unroll 4
        for (int k4 = 0; k4 < 64; ++k4) {
            float4 h4 = hb[k4 * HB_PITCH + img];          // lane-contiguous b128
            const float* wp = wbase + k4 * 4;
            float4 w0 = *(const float4*)(wp + 0 * 256);   // uniform -> s_load
            float4 w1 = *(const float4*)(wp + 1 * 256);
            float4 w2 = *(const float4*)(wp + 2 * 256);
            float4 w3 = *(const float4*)(wp + 3 * 256);
            a0 = fmaf(h4.x,w0.x,a0); a0 = fmaf(h4.y,w0.y,a0); a0 = fmaf(h4.z,w0.z,a0); a0 = fmaf(h4.w,w0.w,a0);
            a1 = fmaf(h4.x,w1.x,a1); a1 = fmaf(h4.y,w1.y,a1); a1 = fmaf(h4.z,w1.z,a1); a1 = fmaf(h4.w,w1.w,a1);
            a2 = fmaf(h4.x,w2.x,a2); a2 = fmaf(h4.y,w2.y,a2); a2 = fmaf(h4.z,w2.z,a2); a2 = fmaf(h4.w,w2.w,a2);
            a3 = fmaf(h4.x,w3.x,a3); a3 = fmaf(h4.y,w3.y,a3); a3 = fmaf(h4.z,w3.z,a3); a3 = fmaf(h4.w,w3.w,a3);
        }

        // bias + square -> h2 (k-major: k4 == w4), lane-contiguous b128 write
        const float* bp = fc1_b + w4 * 4;   // uniform -> s_load
        float4 p0;
        p0.x = a0 + bp[0]; p0.x *= p0.x;
        p0.y = a1 + bp[1]; p0.y *= p0.y;
        p0.z = a2 + bp[2]; p0.z *= p0.z;
        p0.w = a3 + bp[3]; p0.w *= p0.w;
        h2b[w4 * 64 + img] = p0;
    }
    __syncthreads();

    // ---- fc2: first 512 threads; (im3 = t>>3, q = t&7); j = q, and 8+q for q<2 ----
    if (tid < 512) {
        const int im3 = tid >> 3;
        const int q   = tid & 7;

        float s1 = 0.f;
        #pragma unroll
        for (int k4 = 0; k4 < 16; ++k4) {
            float4 hh = h2b[k4 * 64 + im3];
            float4 wA = w2b[k4 * 16 + q];
            s1 = fmaf(hh.x, wA.x, s1); s1 = fmaf(hh.y, wA.y, s1);
            s1 = fmaf(hh.z, wA.z, s1); s1 = fmaf(hh.w, wA.w, s1);
        }
        ob[im3 * 10 + q] = s1 + fc2_b[q];

        if (q < 2) {
            float s2 = 0.f;
            #pragma unroll
            for (int k4 = 0; k4 < 16; ++k4) {
                float4 hh = h2b[k4 * 64 + im3];
                float4 wB = w2b[k4 * 16 + 8 + q];
                s2 = fmaf(hh.x, wB.x, s2); s2 = fmaf(hh.y, wB.y, s2);
                s2 = fmaf(hh.z, wB.z, s2); s2 = fmaf(hh.w, wB.w, s2);
            }
            ob[im3 * 10 + 8 + q] = s2 + fc2_b[8 + q];
        }
    }
    __syncthreads();

    // ---- coalesced output store: 640 floats per block ----
    if (tid < 160) {
        float4 v = *(const float4*)(ob + tid * 4);
        *(float4*)(out + (long)blk * 640 + tid * 4) = v;
    }
}

extern "C" void kernel_launch(void* const* d_in, const int* in_sizes, int n_in,
                              void* d_out, int out_size, void* d_ws, size_t ws_size,
                              hipStream_t stream) {
    const float* x      = (const float*)d_in[0];
    const float* conv_w = (const float*)d_in[1];
    const float* conv_b = (const float*)d_in[2];
    const float* fc1_w  = (const float*)d_in[3];
    const float* fc1_b  = (const float*)d_in[4];
    const float* fc2_w  = (const float*)d_in[5];
    const float* fc2_b  = (const float*)d_in[6];
    float* out = (float*)d_out;

    const int B = in_sizes[0] / 784;
    const int blocks = (B + BLK_IMGS - 1) / BLK_IMGS;   // 1024 for B=65536
    const size_t lds_bytes = LDS_TOTAL_F * sizeof(float);  // 139776

    // gfx950 allows 160 KiB LDS/workgroup; raise the dynamic-LDS cap (idempotent).
    static bool attr_set = false;
    if (!attr_set) {
        (void)hipFuncSetAttribute((const void*)encconv_fused4,
                                  hipFuncAttributeMaxDynamicSharedMemorySize,
                                  (int)lds_bytes);
        attr_set = true;
    }

    encconv_fused4<<<blocks, 1024, lds_bytes, stream>>>(
        x, conv_w, conv_b, fc1_w, fc1_b, fc2_w, fc2_b, out);
}

// Round 3
// 342.451 us; speedup vs baseline: 1.2049x; 1.1943x over previous
//
#include <hip/hip_runtime.h>

// EncConvNet fused v5: conv7x7s3+sq -> fc1+sq -> fc2, one kernel.
// v4 -> v5: kill the spill STRUCTURALLY. v3/v4 spilled the 49-float conv-tap
// array (WRITE_SIZE 2.9 MB -> 186 MB of scratch) because the allocator
// budgets 64 VGPR (dynamic LDS hides the 1-block/CU cap, so it chases 8
// waves/EU; amdgpu_waves_per_eu(4,4) was ignored). Fix: make the conv
// channel c WAVE-UNIFORM (wave = c*4 + img_hi, lane = img_lo*16 + y*2 + xh)
// so the 49 taps load via s_load into SGPRs. Per-thread VGPR demand ~55:
// fits a 64-VGPR budget with zero spill. v_fma_f32 takes the SGPR operand
// directly.
//  - Bank math (mod-32, hand-checked): conv x-read = (16(g&1)+20y+12xh)%32
//    -> 8 lanes per 4-bank group (uniform); hb-write = 4(2y+xh+glo)%32 ->
//    uniform. fc1 read side contiguous. All conflict-free.
//  - 1024 threads/block, 64 imgs/block, LDS 139.8 KB -> 1 block/CU,
//    4 waves/SIMD.
//  - FMA order per output unchanged -> bit-identical to v2/v4.

#define BLK_IMGS    64
#define CHUNK_IMGS  16
#define NCHUNK      4
#define XCH_FLOATS  (CHUNK_IMGS * 784)   // 12544 floats per chunk
#define HB_PITCH    65                   // float4 pitch (bank-conflict pad)

// LDS float offsets
#define LDS_XBUF    0                    // 12544 (single buffer)
#define LDS_H       12544                // 64*65 float4 = 16640 floats
#define LDS_H2      29184                // 16*64 float4 = 4096 floats
#define LDS_W2      33280                // 256 float4 = 1024 floats
#define LDS_OUT     34304                // 640 floats
#define LDS_TOTAL_F 34944                // -> 139776 bytes

__global__ __launch_bounds__(1024)
void encconv_fused5(const float* __restrict__ x,
                    const float* __restrict__ conv_w,
                    const float* __restrict__ conv_b,
                    const float* __restrict__ fc1_w,
                    const float* __restrict__ fc1_b,
                    const float* __restrict__ fc2_w,
                    const float* __restrict__ fc2_b,
                    float* __restrict__ out)
{
    extern __shared__ float lds[];
    float*  xbuf = lds + LDS_XBUF;
    float4* hb   = (float4*)(lds + LDS_H);
    float4* h2b  = (float4*)(lds + LDS_H2);
    float4* w2b  = (float4*)(lds + LDS_W2);
    float*  ob   = lds + LDS_OUT;

    const int tid  = threadIdx.x;
    const int blk  = blockIdx.x;
    const long base_img = (long)blk * BLK_IMGS;

    // ---- conv-phase roles: wave = c*4 + ghi (c uniform per wave!) ----
    //      lane = glo*16 + y*2 + xh ; image g = ghi*4 + glo
    const int lane = tid & 63;
    const int c    = __builtin_amdgcn_readfirstlane((tid >> 6) & 3);
    const int ghi  = __builtin_amdgcn_readfirstlane(tid >> 8);       // 0..3
    const int glo  = lane >> 4;      // 0..3
    const int y    = (lane >> 1) & 7;
    const int xh   = lane & 1;
    const int g    = ghi * 4 + glo;  // image-in-chunk 0..15

    // conv taps: wave-uniform address -> s_load -> SGPRs (zero VGPR cost)
    float ws[49];
    #pragma unroll
    for (int i = 0; i < 49; ++i) ws[i] = conv_w[c * 49 + i];
    const float cb = conv_b[c];

    // stage fc2_w into LDS, k-major: slot = kk*16 + j
    if (tid < 160) {
        float4 v = *(const float4*)(fc2_w + tid * 4);
        int e  = tid * 4;
        int j  = e >> 6;          // 0..9
        int kk = (e & 63) >> 2;   // 0..15
        w2b[kk * 16 + j] = v;
    }

    const float* xblk = x + base_img * 784;

    // ---- prefetch chunk 0 into registers (coalesced: 3136 float4) ----
    float4 pf0, pf1, pf2, pf3;
    {
        const float* src = xblk;
        pf0 = *(const float4*)(src + 4 * tid);
        pf1 = *(const float4*)(src + 4 * (tid + 1024));
        pf2 = *(const float4*)(src + 4 * (tid + 2048));
        if (tid < 64) pf3 = *(const float4*)(src + 4 * (tid + 3072));
    }

    // ---- conv over 4 chunks of 16 images, single-buffered LDS ----
    for (int ch = 0; ch < NCHUNK; ++ch) {
        // commit prefetched regs to LDS (lane-contiguous ds_write_b128)
        *(float4*)(xbuf + 4 * tid)          = pf0;
        *(float4*)(xbuf + 4 * (tid + 1024)) = pf1;
        *(float4*)(xbuf + 4 * (tid + 2048)) = pf2;
        if (tid < 64) *(float4*)(xbuf + 4 * (tid + 3072)) = pf3;
        __syncthreads();

        // issue next chunk's prefetch; conv compute below hides its latency
        if (ch + 1 < NCHUNK) {
            const float* src = xblk + (ch + 1) * XCH_FLOATS;
            pf0 = *(const float4*)(src + 4 * tid);
            pf1 = *(const float4*)(src + 4 * (tid + 1024));
            pf2 = *(const float4*)(src + 4 * (tid + 2048));
            if (tid < 64) pf3 = *(const float4*)(src + 4 * (tid + 3072));
        }

        // conv: image g, row y, channel c (uniform), outputs 4xh..4xh+3
        float acc0 = 0.f, acc1 = 0.f, acc2 = 0.f, acc3 = 0.f;
        const float* xi = xbuf + g * 784;
        #pragma unroll
        for (int rr = 0; rr < 7; ++rr) {
            const float* rp = xi + (3 * y + rr) * 28 + 12 * xh;  // 16B aligned
            float4 r0 = *(const float4*)(rp + 0);
            float4 r1 = *(const float4*)(rp + 4);
            float4 r2 = *(const float4*)(rp + 8);
            float4 r3 = *(const float4*)(rp + 12);
            float r[16] = { r0.x, r0.y, r0.z, r0.w,
                            r1.x, r1.y, r1.z, r1.w,
                            r2.x, r2.y, r2.z, r2.w,
                            r3.x, r3.y, r3.z, r3.w };
            #pragma unroll
            for (int kx = 0; kx < 7; ++kx) {
                const float w = ws[rr * 7 + kx];     // SGPR operand
                acc0 = fmaf(r[0 + kx], w, acc0);
                acc1 = fmaf(r[3 + kx], w, acc1);
                acc2 = fmaf(r[6 + kx], w, acc2);
                acc3 = fmaf(r[9 + kx], w, acc3);
            }
        }

        // bias + square -> h (k-major, padded pitch: slot = k4*65 + img)
        float4 hv;
        hv.x = acc0 + cb; hv.x *= hv.x;
        hv.y = acc1 + cb; hv.y *= hv.y;
        hv.z = acc2 + cb; hv.z *= hv.z;
        hv.w = acc3 + cb; hv.w *= hv.w;
        hb[(c * 16 + y * 2 + xh) * HB_PITCH + (ch * CHUNK_IMGS + g)] = hv;

        // conv reads of xbuf must finish before next chunk's commit;
        // this barrier also publishes hb for fc1 after the last chunk.
        __syncthreads();
    }

    // ---- fc1: wave w4 (0..15) -> outputs 4*w4..4*w4+3, lanes = 64 images ----
    {
        const int img = tid & 63;
        const int w4  = __builtin_amdgcn_readfirstlane(tid >> 6);  // uniform
        const float* wbase = fc1_w + (w4 * 4) * 256;

        float a0 = 0.f, a1 = 0.f, a2 = 0.f, a3 = 0.f;

        #pragma unroll 4
        for (int k4 = 0; k4 < 64; ++k4) {
            float4 h4 = hb[k4 * HB_PITCH + img];          // lane-contiguous b128
            const float* wp = wbase + k4 * 4;
            float4 w0 = *(const float4*)(wp + 0 * 256);   // uniform -> s_load
            float4 w1 = *(const float4*)(wp + 1 * 256);
            float4 w2 = *(const float4*)(wp + 2 * 256);
            float4 w3 = *(const float4*)(wp + 3 * 256);
            a0 = fmaf(h4.x,w0.x,a0); a0 = fmaf(h4.y,w0.y,a0); a0 = fmaf(h4.z,w0.z,a0); a0 = fmaf(h4.w,w0.w,a0);
            a1 = fmaf(h4.x,w1.x,a1); a1 = fmaf(h4.y,w1.y,a1); a1 = fmaf(h4.z,w1.z,a1); a1 = fmaf(h4.w,w1.w,a1);
            a2 = fmaf(h4.x,w2.x,a2); a2 = fmaf(h4.y,w2.y,a2); a2 = fmaf(h4.z,w2.z,a2); a2 = fmaf(h4.w,w2.w,a2);
            a3 = fmaf(h4.x,w3.x,a3); a3 = fmaf(h4.y,w3.y,a3); a3 = fmaf(h4.z,w3.z,a3); a3 = fmaf(h4.w,w3.w,a3);
        }

        // bias + square -> h2 (k-major: k4 == w4), lane-contiguous b128 write
        const float* bp = fc1_b + w4 * 4;   // uniform -> s_load
        float4 p0;
        p0.x = a0 + bp[0]; p0.x *= p0.x;
        p0.y = a1 + bp[1]; p0.y *= p0.y;
        p0.z = a2 + bp[2]; p0.z *= p0.z;
        p0.w = a3 + bp[3]; p0.w *= p0.w;
        h2b[w4 * 64 + img] = p0;
    }
    __syncthreads();

    // ---- fc2: first 512 threads; (im3 = t>>3, q = t&7); j = q, and 8+q for q<2 ----
    if (tid < 512) {
        const int im3 = tid >> 3;
        const int q   = tid & 7;

        float s1 = 0.f;
        #pragma unroll
        for (int k4 = 0; k4 < 16; ++k4) {
            float4 hh = h2b[k4 * 64 + im3];
            float4 wA = w2b[k4 * 16 + q];
            s1 = fmaf(hh.x, wA.x, s1); s1 = fmaf(hh.y, wA.y, s1);
            s1 = fmaf(hh.z, wA.z, s1); s1 = fmaf(hh.w, wA.w, s1);
        }
        ob[im3 * 10 + q] = s1 + fc2_b[q];

        if (q < 2) {
            float s2 = 0.f;
            #pragma unroll
            for (int k4 = 0; k4 < 16; ++k4) {
                float4 hh = h2b[k4 * 64 + im3];
                float4 wB = w2b[k4 * 16 + 8 + q];
                s2 = fmaf(hh.x, wB.x, s2); s2 = fmaf(hh.y, wB.y, s2);
                s2 = fmaf(hh.z, wB.z, s2); s2 = fmaf(hh.w, wB.w, s2);
            }
            ob[im3 * 10 + 8 + q] = s2 + fc2_b[8 + q];
        }
    }
    __syncthreads();

    // ---- coalesced output store: 640 floats per block ----
    if (tid < 160) {
        float4 v = *(const float4*)(ob + tid * 4);
        *(float4*)(out + (long)blk * 640 + tid * 4) = v;
    }
}

extern "C" void kernel_launch(void* const* d_in, const int* in_sizes, int n_in,
                              void* d_out, int out_size, void* d_ws, size_t ws_size,
                              hipStream_t stream) {
    const float* x      = (const float*)d_in[0];
    const float* conv_w = (const float*)d_in[1];
    const float* conv_b = (const float*)d_in[2];
    const float* fc1_w  = (const float*)d_in[3];
    const float* fc1_b  = (const float*)d_in[4];
    const float* fc2_w  = (const float*)d_in[5];
    const float* fc2_b  = (const float*)d_in[6];
    float* out = (float*)d_out;

    const int B = in_sizes[0] / 784;
    const int blocks = (B + BLK_IMGS - 1) / BLK_IMGS;   // 1024 for B=65536
    const size_t lds_bytes = LDS_TOTAL_F * sizeof(float);  // 139776

    // gfx950 allows 160 KiB LDS/workgroup; raise the dynamic-LDS cap (idempotent).
    static bool attr_set = false;
    if (!attr_set) {
        (void)hipFuncSetAttribute((const void*)encconv_fused5,
                                  hipFuncAttributeMaxDynamicSharedMemorySize,
                                  (int)lds_bytes);
        attr_set = true;
    }

    encconv_fused5<<<blocks, 1024, lds_bytes, stream>>>(
        x, conv_w, conv_b, fc1_w, fc1_b, fc2_w, fc2_b, out);
}